// Round 1
// baseline (1358.652 us; speedup 1.0000x reference)
//
#include <hip/hip_runtime.h>
#include <math.h>

#define DM 1024
#define S_LEN 1024

// ---------------- GEMM: C = A @ W + bias (+ resid), all fp32 row-major ----------------
// A: MxK, W: KxN, C: MxN. 64x64 tile, BK=16, 256 threads, 4x4 microtile.
template<bool RESID>
__global__ __launch_bounds__(256) void gemm_bias_kernel(
    const float* __restrict__ A, const float* __restrict__ W,
    const float* __restrict__ bias, const float* __restrict__ resid,
    float* __restrict__ C, int M, int K, int N)
{
    __shared__ __align__(16) float As[16][68];   // [kk][m], stride 68 keeps float4 16B-aligned
    __shared__ __align__(16) float Bs[16][68];   // [kk][n]
    const int tid = threadIdx.x;
    const int tx = tid & 15, ty = tid >> 4;
    const int bm = blockIdx.y * 64, bn = blockIdx.x * 64;

    const int a_m  = tid >> 2;
    const int a_k4 = (tid & 3) << 2;
    const int b_k  = tid >> 4;
    const int b_n4 = (tid & 15) << 2;

    float acc[4][4] = {};

    for (int k0 = 0; k0 < K; k0 += 16) {
        float4 a4 = *reinterpret_cast<const float4*>(&A[(size_t)(bm + a_m) * K + k0 + a_k4]);
        float4 b4 = *reinterpret_cast<const float4*>(&W[(size_t)(k0 + b_k) * N + bn + b_n4]);
        As[a_k4 + 0][a_m] = a4.x;
        As[a_k4 + 1][a_m] = a4.y;
        As[a_k4 + 2][a_m] = a4.z;
        As[a_k4 + 3][a_m] = a4.w;
        *reinterpret_cast<float4*>(&Bs[b_k][b_n4]) = b4;
        __syncthreads();
#pragma unroll
        for (int kk = 0; kk < 16; ++kk) {
            float4 av = *reinterpret_cast<const float4*>(&As[kk][ty << 2]);
            float4 bv = *reinterpret_cast<const float4*>(&Bs[kk][tx << 2]);
            float a[4] = {av.x, av.y, av.z, av.w};
            float b[4] = {bv.x, bv.y, bv.z, bv.w};
#pragma unroll
            for (int i = 0; i < 4; ++i)
#pragma unroll
                for (int j = 0; j < 4; ++j)
                    acc[i][j] = fmaf(a[i], b[j], acc[i][j]);
        }
        __syncthreads();
    }

    float4 bi = *reinterpret_cast<const float4*>(&bias[bn + (tx << 2)]);
#pragma unroll
    for (int i = 0; i < 4; ++i) {
        int row = bm + (ty << 2) + i;
        float4 o;
        o.x = acc[i][0] + bi.x;
        o.y = acc[i][1] + bi.y;
        o.z = acc[i][2] + bi.z;
        o.w = acc[i][3] + bi.w;
        if (RESID) {
            float4 r4 = *reinterpret_cast<const float4*>(&resid[(size_t)row * N + bn + (tx << 2)]);
            o.x += r4.x; o.y += r4.y; o.z += r4.z; o.w += r4.w;
        }
        *reinterpret_cast<float4*>(&C[(size_t)row * N + bn + (tx << 2)]) = o;
    }
}

// ---------------- RoPE (interleaved pairs), in place ----------------
// x: [M, nheads*64]; pair j uses elements (2j, 2j+1); pos = row mod S.
__global__ __launch_bounds__(256) void rope_kernel(float* __restrict__ x, int nheads, int total_pairs)
{
    int idx = blockIdx.x * 256 + threadIdx.x;
    if (idx >= total_pairs) return;
    int j = idx & 31;
    int rh = idx >> 5;                       // row*nheads + h
    int pos = (rh / nheads) & (S_LEN - 1);   // row % S
    // inv_freq = 10000^(-2j/64) = exp2(-j * (2/64)*log2(10000))
    float inv = exp2f((float)j * -0.4152410118609203f);
    float ang = (float)pos * inv;
    float sn, cs;
    sincosf(ang, &sn, &cs);
    size_t base = (size_t)rh * 64 + (j << 1);
    float x1 = x[base], x2 = x[base + 1];
    x[base]     = x1 * cs - x2 * sn;
    x[base + 1] = x1 * sn + x2 * cs;
}

// ---------------- Flash attention (no mask, GQA rep=2) ----------------
// Q: [M, 1024] col h*64+d (pre-RoPE'd), K/V: [M, 512] col kvh*64+d.
// O written in place over Q (block-exclusive region). grid (S/64, H, B), 256 thr.
__global__ __launch_bounds__(256) void attn_kernel(
    const float* __restrict__ Q, const float* __restrict__ K,
    const float* __restrict__ V, float* __restrict__ O)
{
    __shared__ __align__(16) float Qs[64][68];
    __shared__ __align__(16) float KSs[64][68];  // K tile, then overlaid with P (=softmax'd scores)
    __shared__ __align__(16) float Vs[64][68];
    __shared__ float m_s[64], l_s[64], alpha_s[64];
    __shared__ float pm_s[4][64], ps_s[4][64];

    const int tid = threadIdx.x;
    const int tx = tid & 15, ty = tid >> 4;
    const int qt = blockIdx.x, h = blockIdx.y, b = blockIdx.z;
    const int kvh = h >> 1;
    const size_t qrow0 = (size_t)b * S_LEN + (size_t)qt * 64;
    const size_t krow0 = (size_t)b * S_LEN;

    // Load + scale Q tile (64 rows x 64 dims)
    {
        const float scale = 0.125f;  // 1/sqrt(64)
#pragma unroll
        for (int c = 0; c < 4; ++c) {
            int id = c * 256 + tid;
            int r = id >> 4, d4 = (id & 15) << 2;
            float4 q4 = *reinterpret_cast<const float4*>(&Q[(qrow0 + r) * DM + h * 64 + d4]);
            q4.x *= scale; q4.y *= scale; q4.z *= scale; q4.w *= scale;
            *reinterpret_cast<float4*>(&Qs[r][d4]) = q4;
        }
    }
    if (tid < 64) { m_s[tid] = -INFINITY; l_s[tid] = 0.f; }
    float acc[4][4] = {};
    __syncthreads();

    for (int kt = 0; kt < 16; ++kt) {
        // Load K,V tiles
#pragma unroll
        for (int c = 0; c < 4; ++c) {
            int id = c * 256 + tid;
            int r = id >> 4, d4 = (id & 15) << 2;
            size_t g = (krow0 + kt * 64 + r) * 512 + kvh * 64 + d4;
            *reinterpret_cast<float4*>(&KSs[r][d4]) = *reinterpret_cast<const float4*>(&K[g]);
            *reinterpret_cast<float4*>(&Vs[r][d4])  = *reinterpret_cast<const float4*>(&V[g]);
        }
        __syncthreads();

        // Scores in registers: s[i][j] = (scaled Q row)·(K row)
        float s[4][4] = {};
        for (int d0 = 0; d0 < 64; d0 += 4) {
            float4 qa[4], kb[4];
#pragma unroll
            for (int i = 0; i < 4; ++i) qa[i] = *reinterpret_cast<const float4*>(&Qs[(ty << 2) + i][d0]);
#pragma unroll
            for (int j = 0; j < 4; ++j) kb[j] = *reinterpret_cast<const float4*>(&KSs[(tx << 2) + j][d0]);
#pragma unroll
            for (int i = 0; i < 4; ++i)
#pragma unroll
                for (int j = 0; j < 4; ++j) {
                    s[i][j] = fmaf(qa[i].x, kb[j].x, s[i][j]);
                    s[i][j] = fmaf(qa[i].y, kb[j].y, s[i][j]);
                    s[i][j] = fmaf(qa[i].z, kb[j].z, s[i][j]);
                    s[i][j] = fmaf(qa[i].w, kb[j].w, s[i][j]);
                }
        }
        __syncthreads();  // all K-tile reads done before overlaying scores

        // Write scores into KSs (now the S/P tile)
#pragma unroll
        for (int i = 0; i < 4; ++i) {
            float4 o = {s[i][0], s[i][1], s[i][2], s[i][3]};
            *reinterpret_cast<float4*>(&KSs[(ty << 2) + i][tx << 2]) = o;
        }
        __syncthreads();

        // Online softmax: partial max per 16-key segment
        {
            int r = tid & 63, seg = tid >> 6;
            float pmax = -INFINITY;
#pragma unroll
            for (int k2 = 0; k2 < 16; ++k2) pmax = fmaxf(pmax, KSs[r][seg * 16 + k2]);
            pm_s[seg][r] = pmax;
        }
        __syncthreads();
        if (tid < 64) {
            float mt = fmaxf(fmaxf(pm_s[0][tid], pm_s[1][tid]), fmaxf(pm_s[2][tid], pm_s[3][tid]));
            float mo = m_s[tid];
            float mn = fmaxf(mo, mt);
            alpha_s[tid] = __expf(mo - mn);  // first tile: exp(-inf) = 0
            m_s[tid] = mn;
        }
        __syncthreads();
        {
            int r = tid & 63, seg = tid >> 6;
            float mn = m_s[r];
            float psum = 0.f;
#pragma unroll
            for (int k2 = 0; k2 < 16; ++k2) {
                float p = __expf(KSs[r][seg * 16 + k2] - mn);
                KSs[r][seg * 16 + k2] = p;
                psum += p;
            }
            ps_s[seg][r] = psum;
        }
        __syncthreads();
        if (tid < 64)
            l_s[tid] = l_s[tid] * alpha_s[tid] + ps_s[0][tid] + ps_s[1][tid] + ps_s[2][tid] + ps_s[3][tid];

        // Rescale accumulator and add P @ V
#pragma unroll
        for (int i = 0; i < 4; ++i) {
            float al = alpha_s[(ty << 2) + i];
#pragma unroll
            for (int j = 0; j < 4; ++j) acc[i][j] *= al;
        }
        for (int k0 = 0; k0 < 64; k0 += 4) {
            float pv[4][4];
#pragma unroll
            for (int i = 0; i < 4; ++i) {
                float4 t = *reinterpret_cast<const float4*>(&KSs[(ty << 2) + i][k0]);
                pv[i][0] = t.x; pv[i][1] = t.y; pv[i][2] = t.z; pv[i][3] = t.w;
            }
#pragma unroll
            for (int t2 = 0; t2 < 4; ++t2) {
                float4 v4 = *reinterpret_cast<const float4*>(&Vs[k0 + t2][tx << 2]);
#pragma unroll
                for (int i = 0; i < 4; ++i) {
                    acc[i][0] = fmaf(pv[i][t2], v4.x, acc[i][0]);
                    acc[i][1] = fmaf(pv[i][t2], v4.y, acc[i][1]);
                    acc[i][2] = fmaf(pv[i][t2], v4.z, acc[i][2]);
                    acc[i][3] = fmaf(pv[i][t2], v4.w, acc[i][3]);
                }
            }
        }
        __syncthreads();  // protect KSs/Vs before next tile's load
    }

    // Epilogue: normalize by l, write O (in place over Q — block-exclusive region)
#pragma unroll
    for (int i = 0; i < 4; ++i) {
        int r = (ty << 2) + i;
        float rl = 1.0f / l_s[r];
        float4 o = {acc[i][0] * rl, acc[i][1] * rl, acc[i][2] * rl, acc[i][3] * rl};
        *reinterpret_cast<float4*>(&O[(qrow0 + r) * DM + h * 64 + (tx << 2)]) = o;
    }
}

// ---------------- LayerNorm, in place on [8192, 1024] ----------------
__global__ __launch_bounds__(256) void ln_kernel(float* __restrict__ io,
    const float* __restrict__ gamma, const float* __restrict__ beta)
{
    int row = blockIdx.x;
    int tid = threadIdx.x;
    float* p = io + (size_t)row * DM;
    float4 x = *reinterpret_cast<const float4*>(&p[tid << 2]);
    float s  = x.x + x.y + x.z + x.w;
    float ss = fmaf(x.x, x.x, fmaf(x.y, x.y, fmaf(x.z, x.z, x.w * x.w)));
#pragma unroll
    for (int off = 32; off > 0; off >>= 1) {
        s  += __shfl_down(s,  off);
        ss += __shfl_down(ss, off);
    }
    __shared__ float rs[4], rss[4];
    int lane = tid & 63, wid = tid >> 6;
    if (lane == 0) { rs[wid] = s; rss[wid] = ss; }
    __syncthreads();
    float S  = rs[0] + rs[1] + rs[2] + rs[3];
    float SS = rss[0] + rss[1] + rss[2] + rss[3];
    float mu  = S * (1.0f / 1024.0f);
    float var = SS * (1.0f / 1024.0f) - mu * mu;
    float rstd = rsqrtf(var + 1e-12f);
    float4 g  = *reinterpret_cast<const float4*>(&gamma[tid << 2]);
    float4 be = *reinterpret_cast<const float4*>(&beta[tid << 2]);
    float4 o;
    o.x = (x.x - mu) * rstd * g.x + be.x;
    o.y = (x.y - mu) * rstd * g.y + be.y;
    o.z = (x.z - mu) * rstd * g.z + be.z;
    o.w = (x.w - mu) * rstd * g.w + be.w;
    *reinterpret_cast<float4*>(&p[tid << 2]) = o;
}

// ---------------- launch ----------------
extern "C" void kernel_launch(void* const* d_in, const int* in_sizes, int n_in,
                              void* d_out, int out_size, void* d_ws, size_t ws_size,
                              hipStream_t stream)
{
    (void)in_sizes; (void)n_in; (void)out_size; (void)ws_size;
    const float* hidden = (const float*)d_in[0];
    const float* Wq = (const float*)d_in[1];
    const float* bq = (const float*)d_in[2];
    const float* Wk = (const float*)d_in[3];
    const float* bk = (const float*)d_in[4];
    const float* Wv = (const float*)d_in[5];
    const float* bv = (const float*)d_in[6];
    const float* Wo = (const float*)d_in[7];
    const float* bo = (const float*)d_in[8];
    const float* g  = (const float*)d_in[9];
    const float* be = (const float*)d_in[10];
    float* out = (float*)d_out;

    float* Qb = (float*)d_ws;                       // 8192*1024 f32 = 33.5 MB (also attn out)
    float* Kb = Qb + (size_t)8192 * 1024;           // 8192*512
    float* Vb = Kb + (size_t)8192 * 512;            // 8192*512  -> total 67 MB

    dim3 blk(256);
    // QKV projections
    gemm_bias_kernel<false><<<dim3(16, 128), blk, 0, stream>>>(hidden, Wq, bq, nullptr, Qb, 8192, 1024, 1024);
    gemm_bias_kernel<false><<<dim3(8, 128),  blk, 0, stream>>>(hidden, Wk, bk, nullptr, Kb, 8192, 1024, 512);
    gemm_bias_kernel<false><<<dim3(8, 128),  blk, 0, stream>>>(hidden, Wv, bv, nullptr, Vb, 8192, 1024, 512);
    // RoPE on Q (16 heads) and K (8 heads)
    rope_kernel<<<dim3(4194304 / 256), blk, 0, stream>>>(Qb, 16, 4194304);
    rope_kernel<<<dim3(2097152 / 256), blk, 0, stream>>>(Kb, 8, 2097152);
    // Flash attention (O in place over Q)
    attn_kernel<<<dim3(16, 16, 8), blk, 0, stream>>>(Qb, Kb, Vb, Qb);
    // Output projection + bias + residual -> d_out
    gemm_bias_kernel<true><<<dim3(16, 128), blk, 0, stream>>>(Qb, Wo, bo, hidden, out, 8192, 1024, 1024);
    // LayerNorm in place on d_out
    ln_kernel<<<dim3(8192), blk, 0, stream>>>(out, g, be);
}

// Round 2
// 407.178 us; speedup vs baseline: 3.3368x; 3.3368x over previous
//
#include <hip/hip_runtime.h>
#include <math.h>
#include <stdint.h>

typedef unsigned short u16;
typedef __bf16 bf16x8 __attribute__((ext_vector_type(8)));
typedef float f32x4 __attribute__((ext_vector_type(4)));

typedef const __attribute__((address_space(1))) void gv_t;
typedef __attribute__((address_space(3))) void lv_t;

__device__ __forceinline__ u16 f2bf(float f) {
    unsigned u = __builtin_bit_cast(unsigned, f);
    return (u16)((u + 0x7FFFu + ((u >> 16) & 1u)) >> 16);
}
__device__ __forceinline__ float bf2f(u16 h) {
    return __builtin_bit_cast(float, (unsigned)h << 16);
}
// async global->LDS, 16B per lane; LDS dest = wave-uniform base + lane*16
__device__ __forceinline__ void gll16(const void* g, void* l) {
    __builtin_amdgcn_global_load_lds((gv_t*)(uintptr_t)g,
                                     (lv_t*)(unsigned)(uintptr_t)l, 16, 0, 0);
}

// ---------------- fp32 -> bf16 elementwise ----------------
__global__ __launch_bounds__(256) void cvt_bf16_kernel(
    const float* __restrict__ in, u16* __restrict__ out, int n4)
{
    int i = blockIdx.x * 256 + threadIdx.x;
    if (i >= n4) return;
    float4 f = ((const float4*)in)[i];
    ushort4 o = make_ushort4(f2bf(f.x), f2bf(f.y), f2bf(f.z), f2bf(f.w));
    ((ushort4*)out)[i] = o;
}

// ---------------- fp32 [K][N] -> bf16 [N][K] transpose ----------------
__global__ __launch_bounds__(256) void cvt_t_kernel(
    const float* __restrict__ in, u16* __restrict__ out, int K, int N)
{
    __shared__ u16 t[64][65];
    int kb = blockIdx.y * 64, nb = blockIdx.x * 64;
    int tid = threadIdx.x;
#pragma unroll
    for (int c = 0; c < 16; ++c) {
        int id = c * 256 + tid;
        int r = id >> 6, n = id & 63;
        t[n][r] = f2bf(in[(size_t)(kb + r) * N + nb + n]);
    }
    __syncthreads();
#pragma unroll
    for (int c = 0; c < 16; ++c) {
        int id = c * 256 + tid;
        int r = id >> 6, n = id & 63;
        out[(size_t)(nb + r) * K + kb + n] = t[r][n];
    }
}

// ---------------- MFMA GEMM: C = A @ Bt^T (+bias) (+resid) ----------------
// A: [M][K] bf16, Bt: [N][K] bf16. 128x128 tile, BK=32, 256 thr = 4 waves 2x2.
template<int FP32_OUT>
__global__ __launch_bounds__(256) void gemm_mfma(
    const u16* __restrict__ A, const u16* __restrict__ Bt,
    const float* __restrict__ bias, const float* __restrict__ bias2, int nsplit,
    const float* __restrict__ resid, void* __restrict__ Cv,
    int M, int N, int K)
{
    __shared__ __align__(16) u16 Asl[128 * 32];
    __shared__ __align__(16) u16 Bsl[128 * 32];
    const int tid = threadIdx.x, lane = tid & 63, w = tid >> 6;
    const int quad = lane >> 4, l16 = lane & 15;
    const int bm = blockIdx.y * 128, bn = blockIdx.x * 128;
    const int wm = (w >> 1) * 64, wn = (w & 1) * 64;

    f32x4 acc[4][4] = {};

    const int sr = w * 16 + (lane >> 2);   // staging row (per-lane), matches lds base+lane*16
    const int sk = (lane & 3) << 3;
    const u16* Ag0 = &A[(size_t)(bm + sr) * K + sk];
    const u16* Ag1 = &A[(size_t)(bm + 64 + sr) * K + sk];
    const u16* Bg0 = &Bt[(size_t)(bn + sr) * K + sk];
    const u16* Bg1 = &Bt[(size_t)(bn + 64 + sr) * K + sk];
    u16* Al0 = &Asl[(w * 16) * 32];
    u16* Al1 = &Asl[(w * 16 + 64) * 32];
    u16* Bl0 = &Bsl[(w * 16) * 32];
    u16* Bl1 = &Bsl[(w * 16 + 64) * 32];

    for (int k0 = 0; k0 < K; k0 += 32) {
        gll16(Ag0 + k0, Al0);
        gll16(Ag1 + k0, Al1);
        gll16(Bg0 + k0, Bl0);
        gll16(Bg1 + k0, Bl1);
        __syncthreads();   // drains vmcnt -> staged data visible
        bf16x8 af[4], bfr[4];
#pragma unroll
        for (int i = 0; i < 4; ++i)
            af[i] = *(const bf16x8*)&Asl[(wm + i * 16 + l16) * 32 + quad * 8];
#pragma unroll
        for (int j = 0; j < 4; ++j)
            bfr[j] = *(const bf16x8*)&Bsl[(wn + j * 16 + l16) * 32 + quad * 8];
#pragma unroll
        for (int i = 0; i < 4; ++i)
#pragma unroll
            for (int j = 0; j < 4; ++j)
                acc[i][j] = __builtin_amdgcn_mfma_f32_16x16x32_bf16(af[i], bfr[j], acc[i][j], 0, 0, 0);
        __syncthreads();   // LDS reads done before next stage overwrites
    }

    // epilogue: C/D layout col=lane&15, row=quad*4+reg
#pragma unroll
    for (int j = 0; j < 4; ++j) {
        int col = bn + wn + j * 16 + l16;
        float bv_ = (col < nsplit) ? bias[col] : bias2[col - nsplit];
#pragma unroll
        for (int i = 0; i < 4; ++i) {
            int row0 = bm + wm + i * 16 + quad * 4;
#pragma unroll
            for (int r = 0; r < 4; ++r) {
                float o = acc[i][j][r] + bv_;
                size_t off = (size_t)(row0 + r) * N + col;
                if (FP32_OUT) ((float*)Cv)[off] = o + resid[off];
                else          ((u16*)Cv)[off] = f2bf(o);
            }
        }
    }
}

// ---------------- RoPE (interleaved), in place on bf16 ----------------
__global__ __launch_bounds__(256) void rope_bf16_kernel(
    u16* __restrict__ x, int shift, int stride, int total)
{
    int idx = blockIdx.x * 256 + threadIdx.x;
    if (idx >= total) return;
    int j = idx & 31;
    int h = (idx >> 5) & ((1 << shift) - 1);
    int row = idx >> (5 + shift);
    int pos = row & 1023;
    float inv = exp2f((float)j * -0.4152410118609203f);  // 10000^(-2j/64)
    float sn, cs;
    sincosf((float)pos * inv, &sn, &cs);
    unsigned* p = (unsigned*)&x[(size_t)row * stride + h * 64 + (j << 1)];
    unsigned u = *p;
    float x1 = bf2f((u16)(u & 0xffff)), x2 = bf2f((u16)(u >> 16));
    float y1 = x1 * cs - x2 * sn, y2 = x1 * sn + x2 * cs;
    *p = (unsigned)f2bf(y1) | ((unsigned)f2bf(y2) << 16);
}

// ---------------- MFMA flash attention ----------------
// Q: [8192][1024] bf16 (h*64+d). KV: [8192][1024]: cols 0-511 K (kvh*64+d), 512-1023 V.
// O over Q in place (block-exclusive). grid (16 qt, 16 h, 8 b), 256 thr = 4 waves.
__global__ __launch_bounds__(256) void attn_mfma(
    const u16* __restrict__ Q, const u16* __restrict__ KV, u16* __restrict__ O)
{
    __shared__ __align__(16) u16 Qs[64][72];
    __shared__ __align__(16) u16 Ks[64][72];
    __shared__ __align__(16) u16 Vt[64][72];   // [d][key]
    __shared__ __align__(16) u16 Ps[64][72];   // [qrow][key]

    const int tid = threadIdx.x, lane = tid & 63, w = tid >> 6;
    const int quad = lane >> 4, l16 = lane & 15;
    const int qt = blockIdx.x, h = blockIdx.y, b = blockIdx.z;
    const int kvh = h >> 1;
    const size_t qrow0 = (size_t)b * 1024 + qt * 64;
    const size_t krow0 = (size_t)b * 1024;

#pragma unroll
    for (int c = 0; c < 2; ++c) {
        int id = c * 256 + tid;
        int r = id >> 3, d0 = (id & 7) << 3;
        *(uint4*)&Qs[r][d0] = *(const uint4*)&Q[(qrow0 + r) * 1024 + h * 64 + d0];
    }
    f32x4 acc_o[4] = {};
    float m_i[4] = {-INFINITY, -INFINITY, -INFINITY, -INFINITY};
    float l_i[4] = {0.f, 0.f, 0.f, 0.f};
    __syncthreads();

    for (int kt = 0; kt < 16; ++kt) {
        // stage K natural, V transposed
#pragma unroll
        for (int c = 0; c < 2; ++c) {
            int id = c * 256 + tid;
            int r = id >> 3, d0 = (id & 7) << 3;
            *(uint4*)&Ks[r][d0] = *(const uint4*)&KV[(krow0 + kt * 64 + r) * 1024 + kvh * 64 + d0];
            uint4 v = *(const uint4*)&KV[(krow0 + kt * 64 + r) * 1024 + 512 + kvh * 64 + d0];
            Vt[d0 + 0][r] = (u16)(v.x & 0xffff); Vt[d0 + 1][r] = (u16)(v.x >> 16);
            Vt[d0 + 2][r] = (u16)(v.y & 0xffff); Vt[d0 + 3][r] = (u16)(v.y >> 16);
            Vt[d0 + 4][r] = (u16)(v.z & 0xffff); Vt[d0 + 5][r] = (u16)(v.z >> 16);
            Vt[d0 + 6][r] = (u16)(v.w & 0xffff); Vt[d0 + 7][r] = (u16)(v.w >> 16);
        }
        __syncthreads();

        // S = Q K^T : wave w owns q-rows w*16..+15, all 64 keys
        f32x4 s[4] = {};
#pragma unroll
        for (int ks = 0; ks < 2; ++ks) {
            bf16x8 aq = *(const bf16x8*)&Qs[w * 16 + l16][ks * 32 + quad * 8];
#pragma unroll
            for (int nt = 0; nt < 4; ++nt) {
                bf16x8 bk = *(const bf16x8*)&Ks[nt * 16 + l16][ks * 32 + quad * 8];
                s[nt] = __builtin_amdgcn_mfma_f32_16x16x32_bf16(aq, bk, s[nt], 0, 0, 0);
            }
        }

        // online softmax in C-layout (row = w*16 + quad*4 + i, col = nt*16 + l16)
        float alpha[4];
#pragma unroll
        for (int i = 0; i < 4; ++i) {
            float mx = fmaxf(fmaxf(s[0][i], s[1][i]), fmaxf(s[2][i], s[3][i])) * 0.125f;
#pragma unroll
            for (int off = 1; off < 16; off <<= 1) mx = fmaxf(mx, __shfl_xor(mx, off));
            float mn = fmaxf(m_i[i], mx);
            alpha[i] = __expf(m_i[i] - mn);
            m_i[i] = mn;
            float sum = 0.f;
#pragma unroll
            for (int nt = 0; nt < 4; ++nt) {
                float p = __expf(fmaf(s[nt][i], 0.125f, -mn));
                sum += p;
                Ps[w * 16 + quad * 4 + i][nt * 16 + l16] = f2bf(p);
            }
#pragma unroll
            for (int off = 1; off < 16; off <<= 1) sum += __shfl_xor(sum, off);
            l_i[i] = l_i[i] * alpha[i] + sum;
        }
#pragma unroll
        for (int nt = 0; nt < 4; ++nt)
#pragma unroll
            for (int i = 0; i < 4; ++i) acc_o[nt][i] *= alpha[i];
        __syncthreads();   // P visible (cross-lane) before A-frag reads

        // O += P V : A-frag from Ps, B-frag from Vt
#pragma unroll
        for (int ks = 0; ks < 2; ++ks) {
            bf16x8 ap = *(const bf16x8*)&Ps[w * 16 + l16][ks * 32 + quad * 8];
#pragma unroll
            for (int nt = 0; nt < 4; ++nt) {
                bf16x8 bv = *(const bf16x8*)&Vt[nt * 16 + l16][ks * 32 + quad * 8];
                acc_o[nt] = __builtin_amdgcn_mfma_f32_16x16x32_bf16(ap, bv, acc_o[nt], 0, 0, 0);
            }
        }
        __syncthreads();   // Ks/Vt reads done before next stage
    }

#pragma unroll
    for (int nt = 0; nt < 4; ++nt)
#pragma unroll
        for (int i = 0; i < 4; ++i) {
            float o = acc_o[nt][i] / l_i[i];
            O[(qrow0 + w * 16 + quad * 4 + i) * 1024 + h * 64 + nt * 16 + l16] = f2bf(o);
        }
}

// ---------------- LayerNorm in place on [8192][1024] fp32 ----------------
__global__ __launch_bounds__(256) void ln_kernel(float* __restrict__ io,
    const float* __restrict__ gamma, const float* __restrict__ beta)
{
    int row = blockIdx.x;
    int tid = threadIdx.x;
    float* p = io + (size_t)row * 1024;
    float4 x = *reinterpret_cast<const float4*>(&p[tid << 2]);
    float s = x.x + x.y + x.z + x.w;
    float ss = fmaf(x.x, x.x, fmaf(x.y, x.y, fmaf(x.z, x.z, x.w * x.w)));
#pragma unroll
    for (int off = 32; off > 0; off >>= 1) {
        s  += __shfl_down(s, off);
        ss += __shfl_down(ss, off);
    }
    __shared__ float rs[4], rss[4];
    int lane = tid & 63, wid = tid >> 6;
    if (lane == 0) { rs[wid] = s; rss[wid] = ss; }
    __syncthreads();
    float S = rs[0] + rs[1] + rs[2] + rs[3];
    float SS = rss[0] + rss[1] + rss[2] + rss[3];
    float mu = S * (1.0f / 1024.0f);
    float var = SS * (1.0f / 1024.0f) - mu * mu;
    float rstd = rsqrtf(var + 1e-12f);
    float4 g = *reinterpret_cast<const float4*>(&gamma[tid << 2]);
    float4 be = *reinterpret_cast<const float4*>(&beta[tid << 2]);
    float4 o;
    o.x = (x.x - mu) * rstd * g.x + be.x;
    o.y = (x.y - mu) * rstd * g.y + be.y;
    o.z = (x.z - mu) * rstd * g.z + be.z;
    o.w = (x.w - mu) * rstd * g.w + be.w;
    *reinterpret_cast<float4*>(&p[tid << 2]) = o;
}

// ---------------- launch ----------------
extern "C" void kernel_launch(void* const* d_in, const int* in_sizes, int n_in,
                              void* d_out, int out_size, void* d_ws, size_t ws_size,
                              hipStream_t stream)
{
    (void)in_sizes; (void)n_in; (void)out_size; (void)ws_size;
    const float* hidden = (const float*)d_in[0];
    const float* Wq = (const float*)d_in[1];
    const float* bq = (const float*)d_in[2];
    const float* Wk = (const float*)d_in[3];
    const float* bk = (const float*)d_in[4];
    const float* Wv = (const float*)d_in[5];
    const float* bv = (const float*)d_in[6];
    const float* Wo = (const float*)d_in[7];
    const float* bo = (const float*)d_in[8];
    const float* g  = (const float*)d_in[9];
    const float* be = (const float*)d_in[10];
    float* out = (float*)d_out;

    u16* hb  = (u16*)d_ws;                       // [8192][1024] bf16 hidden
    u16* Wqt = hb  + (size_t)8192 * 1024;        // [1024][1024] Wq^T
    u16* Wkt = Wqt + (size_t)1024 * 1024;        // [512][1024]  Wk^T
    u16* Wvt = Wkt + (size_t)512 * 1024;         // [512][1024]  Wv^T (contiguous after Wkt)
    u16* Wot = Wvt + (size_t)512 * 1024;         // [1024][1024] Wo^T
    u16* Qb  = Wot + (size_t)1024 * 1024;        // [8192][1024] Q (then attn out)
    u16* KVb = Qb  + (size_t)8192 * 1024;        // [8192][1024] cols 0-511 K, 512-1023 V
    // total 56.3 MB

    cvt_bf16_kernel<<<8192, 256, 0, stream>>>(hidden, hb, 8192 * 1024 / 4);
    cvt_t_kernel<<<dim3(16, 16), 256, 0, stream>>>(Wq, Wqt, 1024, 1024);
    cvt_t_kernel<<<dim3(8, 16),  256, 0, stream>>>(Wk, Wkt, 1024, 512);
    cvt_t_kernel<<<dim3(8, 16),  256, 0, stream>>>(Wv, Wvt, 1024, 512);
    cvt_t_kernel<<<dim3(16, 16), 256, 0, stream>>>(Wo, Wot, 1024, 1024);

    gemm_mfma<0><<<dim3(8, 64), 256, 0, stream>>>(hb, Wqt, bq, bq, 1024, nullptr, Qb, 8192, 1024, 1024);
    gemm_mfma<0><<<dim3(8, 64), 256, 0, stream>>>(hb, Wkt, bk, bv, 512,  nullptr, KVb, 8192, 1024, 1024);

    rope_bf16_kernel<<<16384, 256, 0, stream>>>(Qb, 4, 1024, 8192 * 16 * 32);
    rope_bf16_kernel<<<8192, 256, 0, stream>>>(KVb, 3, 1024, 8192 * 8 * 32);

    attn_mfma<<<dim3(16, 16, 8), 256, 0, stream>>>(Qb, KVb, Qb);

    gemm_mfma<1><<<dim3(8, 64), 256, 0, stream>>>(Qb, Wot, bo, bo, 1024, hidden, out, 8192, 1024, 1024);
    ln_kernel<<<8192, 256, 0, stream>>>(out, g, be);
}

// Round 3
// 365.933 us; speedup vs baseline: 3.7128x; 1.1127x over previous
//
#include <hip/hip_runtime.h>
#include <math.h>
#include <stdint.h>

typedef unsigned short u16;
typedef __bf16 bf16x8 __attribute__((ext_vector_type(8)));
typedef float f32x4 __attribute__((ext_vector_type(4)));

typedef const __attribute__((address_space(1))) void gv_t;
typedef __attribute__((address_space(3))) void lv_t;

__device__ __forceinline__ u16 f2bf(float f) {
    unsigned u = __builtin_bit_cast(unsigned, f);
    return (u16)((u + 0x7FFFu + ((u >> 16) & 1u)) >> 16);
}
__device__ __forceinline__ float bf2f(u16 h) {
    return __builtin_bit_cast(float, (unsigned)h << 16);
}
// async global->LDS, 16B per lane; LDS dest = wave-uniform base + lane*16
__device__ __forceinline__ void gll16(const void* g, void* l) {
    __builtin_amdgcn_global_load_lds((gv_t*)(uintptr_t)g,
                                     (lv_t*)(unsigned)(uintptr_t)l, 16, 0, 0);
}

// ---------------- fp32 -> bf16 elementwise ----------------
__global__ __launch_bounds__(256) void cvt_bf16_kernel(
    const float* __restrict__ in, u16* __restrict__ out, int n4)
{
    int i = blockIdx.x * 256 + threadIdx.x;
    if (i >= n4) return;
    float4 f = ((const float4*)in)[i];
    ushort4 o = make_ushort4(f2bf(f.x), f2bf(f.y), f2bf(f.z), f2bf(f.w));
    ((ushort4*)out)[i] = o;
}

// ---------------- fp32 [K][N] -> bf16 [N][K] transpose ----------------
__global__ __launch_bounds__(256) void cvt_t_kernel(
    const float* __restrict__ in, u16* __restrict__ out, int K, int N)
{
    __shared__ u16 t[64][65];
    int kb = blockIdx.y * 64, nb = blockIdx.x * 64;
    int tid = threadIdx.x;
#pragma unroll
    for (int c = 0; c < 16; ++c) {
        int id = c * 256 + tid;
        int r = id >> 6, n = id & 63;
        t[n][r] = f2bf(in[(size_t)(kb + r) * N + nb + n]);
    }
    __syncthreads();
#pragma unroll
    for (int c = 0; c < 16; ++c) {
        int id = c * 256 + tid;
        int r = id >> 6, n = id & 63;
        out[(size_t)(nb + r) * K + kb + n] = t[r][n];
    }
}

// ---------------- MFMA GEMM: C = A @ Bt^T (+bias) ----------------
// A: [M][K] bf16, Bt: [N][K] bf16. 128x128 tile, BK=32, 256 thr = 4 waves 2x2.
// MODE 0: bf16 natural out. MODE 1: fp32 out + resid. MODE 2: KV — cols<512
// natural bf16 K (bias), cols>=512 V written TRANSPOSED to Vt (bias2):
// Vt[((b*8+kvh)*64+d)*1024 + s], packed ushort4 along s.
template<int MODE>
__global__ __launch_bounds__(256) void gemm_mfma(
    const u16* __restrict__ A, const u16* __restrict__ Bt,
    const float* __restrict__ bias, const float* __restrict__ bias2,
    const float* __restrict__ resid, void* __restrict__ Cv, u16* __restrict__ Vt,
    int M, int N, int K)
{
    __shared__ __align__(16) u16 Asl[128 * 32];
    __shared__ __align__(16) u16 Bsl[128 * 32];
    const int tid = threadIdx.x, lane = tid & 63, w = tid >> 6;
    const int quad = lane >> 4, l16 = lane & 15;
    const int bm = blockIdx.y * 128, bn = blockIdx.x * 128;
    const int wm = (w >> 1) * 64, wn = (w & 1) * 64;

    f32x4 acc[4][4] = {};

    const int sr = w * 16 + (lane >> 2);   // staging row (per-lane), matches lds base+lane*16
    const int sk = (lane & 3) << 3;
    const u16* Ag0 = &A[(size_t)(bm + sr) * K + sk];
    const u16* Ag1 = &A[(size_t)(bm + 64 + sr) * K + sk];
    const u16* Bg0 = &Bt[(size_t)(bn + sr) * K + sk];
    const u16* Bg1 = &Bt[(size_t)(bn + 64 + sr) * K + sk];
    u16* Al0 = &Asl[(w * 16) * 32];
    u16* Al1 = &Asl[(w * 16 + 64) * 32];
    u16* Bl0 = &Bsl[(w * 16) * 32];
    u16* Bl1 = &Bsl[(w * 16 + 64) * 32];

    for (int k0 = 0; k0 < K; k0 += 32) {
        gll16(Ag0 + k0, Al0);
        gll16(Ag1 + k0, Al1);
        gll16(Bg0 + k0, Bl0);
        gll16(Bg1 + k0, Bl1);
        __syncthreads();   // drains vmcnt -> staged data visible
        bf16x8 af[4], bfr[4];
#pragma unroll
        for (int i = 0; i < 4; ++i)
            af[i] = *(const bf16x8*)&Asl[(wm + i * 16 + l16) * 32 + quad * 8];
#pragma unroll
        for (int j = 0; j < 4; ++j)
            bfr[j] = *(const bf16x8*)&Bsl[(wn + j * 16 + l16) * 32 + quad * 8];
#pragma unroll
        for (int i = 0; i < 4; ++i)
#pragma unroll
            for (int j = 0; j < 4; ++j)
                acc[i][j] = __builtin_amdgcn_mfma_f32_16x16x32_bf16(af[i], bfr[j], acc[i][j], 0, 0, 0);
        __syncthreads();   // LDS reads done before next stage overwrites
    }

    // epilogue: C/D layout col=lane&15, row=quad*4+reg
#pragma unroll
    for (int j = 0; j < 4; ++j) {
        int col = bn + wn + j * 16 + l16;
        if (MODE == 2 && col >= 512) {
            int cv = col - 512, kvh = cv >> 6, d = cv & 63;
            float bb = bias2[cv];
#pragma unroll
            for (int i = 0; i < 4; ++i) {
                int row0 = bm + wm + i * 16 + quad * 4;
                int b = row0 >> 10, s = row0 & 1023;
                ushort4 o4;
                o4.x = f2bf(acc[i][j][0] + bb);
                o4.y = f2bf(acc[i][j][1] + bb);
                o4.z = f2bf(acc[i][j][2] + bb);
                o4.w = f2bf(acc[i][j][3] + bb);
                *(ushort4*)&Vt[(size_t)((b * 8 + kvh) * 64 + d) * 1024 + s] = o4;
            }
        } else {
            float bb = bias[col];
#pragma unroll
            for (int i = 0; i < 4; ++i) {
                int row0 = bm + wm + i * 16 + quad * 4;
#pragma unroll
                for (int r = 0; r < 4; ++r) {
                    float o = acc[i][j][r] + bb;
                    size_t off = (size_t)(row0 + r) * N + col;
                    if (MODE == 1) ((float*)Cv)[off] = o + resid[off];
                    else           ((u16*)Cv)[off] = f2bf(o);
                }
            }
        }
    }
}

// ---------------- RoPE (interleaved), in place on bf16 ----------------
__global__ __launch_bounds__(256) void rope_bf16_kernel(
    u16* __restrict__ x, int shift, int stride, int total)
{
    int idx = blockIdx.x * 256 + threadIdx.x;
    if (idx >= total) return;
    int j = idx & 31;
    int h = (idx >> 5) & ((1 << shift) - 1);
    int row = idx >> (5 + shift);
    int pos = row & 1023;
    float inv = exp2f((float)j * -0.4152410118609203f);  // 10000^(-2j/64)
    float sn, cs;
    sincosf((float)pos * inv, &sn, &cs);
    unsigned* p = (unsigned*)&x[(size_t)row * stride + h * 64 + (j << 1)];
    unsigned u = *p;
    float x1 = bf2f((u16)(u & 0xffff)), x2 = bf2f((u16)(u >> 16));
    float y1 = x1 * cs - x2 * sn, y2 = x1 * sn + x2 * cs;
    *p = (unsigned)f2bf(y1) | ((unsigned)f2bf(y2) << 16);
}

// ---------------- MFMA flash attention ----------------
// Q: [8192][1024] bf16 (h*64+d). K: [8192][1024] cols 0-511 (kvh*64+d).
// Vt: [(b*8+kvh)*64+d][1024 keys] bf16 (pre-transposed).
// O over Q in place (block-exclusive). grid (16 qt, 16 h, 8 b), 256 thr = 4 waves.
__global__ __launch_bounds__(256) void attn_mfma(
    const u16* __restrict__ Q, const u16* __restrict__ K,
    const u16* __restrict__ Vt, u16* __restrict__ O)
{
    __shared__ __align__(16) u16 Qs[64][72];
    __shared__ __align__(16) u16 Ks[64][72];
    __shared__ __align__(16) u16 Vts[64][72];  // [d][key]
    __shared__ __align__(16) u16 Ps[64][72];   // [qrow][key]

    const int tid = threadIdx.x, lane = tid & 63, w = tid >> 6;
    const int quad = lane >> 4, l16 = lane & 15;
    const int qt = blockIdx.x, h = blockIdx.y, b = blockIdx.z;
    const int kvh = h >> 1;
    const size_t qrow0 = (size_t)b * 1024 + qt * 64;
    const size_t krow0 = (size_t)b * 1024;
    const u16* Vg = Vt + (size_t)((b * 8 + kvh) * 64) * 1024;

    const int sr = tid >> 3, sc = (tid & 7) << 3;  // 32 rows per 256-thread pass

#pragma unroll
    for (int c = 0; c < 2; ++c) {
        int r = c * 32 + sr;
        *(uint4*)&Qs[r][sc] = *(const uint4*)&Q[(qrow0 + r) * 1024 + h * 64 + sc];
    }
    f32x4 acc_o[4] = {};
    float m_i[4] = {-INFINITY, -INFINITY, -INFINITY, -INFINITY};
    float l_i[4] = {0.f, 0.f, 0.f, 0.f};
    __syncthreads();

    for (int kt = 0; kt < 16; ++kt) {
        // stage K natural, V^T from pre-transposed global (both coalesced uint4)
#pragma unroll
        for (int c = 0; c < 2; ++c) {
            int r = c * 32 + sr;
            *(uint4*)&Ks[r][sc]  = *(const uint4*)&K[(krow0 + kt * 64 + r) * 1024 + kvh * 64 + sc];
            *(uint4*)&Vts[r][sc] = *(const uint4*)&Vg[(size_t)r * 1024 + kt * 64 + sc];
        }
        __syncthreads();

        // S = Q K^T : wave w owns q-rows w*16..+15, all 64 keys
        f32x4 s[4] = {};
#pragma unroll
        for (int ks = 0; ks < 2; ++ks) {
            bf16x8 aq = *(const bf16x8*)&Qs[w * 16 + l16][ks * 32 + quad * 8];
#pragma unroll
            for (int nt = 0; nt < 4; ++nt) {
                bf16x8 bk = *(const bf16x8*)&Ks[nt * 16 + l16][ks * 32 + quad * 8];
                s[nt] = __builtin_amdgcn_mfma_f32_16x16x32_bf16(aq, bk, s[nt], 0, 0, 0);
            }
        }

        // online softmax in C-layout (row = w*16 + quad*4 + i, col = nt*16 + l16)
        float alpha[4];
#pragma unroll
        for (int i = 0; i < 4; ++i) {
            float mx = fmaxf(fmaxf(s[0][i], s[1][i]), fmaxf(s[2][i], s[3][i])) * 0.125f;
#pragma unroll
            for (int off = 1; off < 16; off <<= 1) mx = fmaxf(mx, __shfl_xor(mx, off));
            float mn = fmaxf(m_i[i], mx);
            alpha[i] = __expf(m_i[i] - mn);
            m_i[i] = mn;
            float sum = 0.f;
#pragma unroll
            for (int nt = 0; nt < 4; ++nt) {
                float p = __expf(fmaf(s[nt][i], 0.125f, -mn));
                sum += p;
                Ps[w * 16 + quad * 4 + i][nt * 16 + l16] = f2bf(p);
            }
#pragma unroll
            for (int off = 1; off < 16; off <<= 1) sum += __shfl_xor(sum, off);
            l_i[i] = l_i[i] * alpha[i] + sum;
        }
#pragma unroll
        for (int nt = 0; nt < 4; ++nt)
#pragma unroll
            for (int i = 0; i < 4; ++i) acc_o[nt][i] *= alpha[i];
        __syncthreads();   // P visible (cross-lane) before A-frag reads

        // O += P V : A-frag from Ps, B-frag from Vts ([d][key])
#pragma unroll
        for (int ks = 0; ks < 2; ++ks) {
            bf16x8 ap = *(const bf16x8*)&Ps[w * 16 + l16][ks * 32 + quad * 8];
#pragma unroll
            for (int nt = 0; nt < 4; ++nt) {
                bf16x8 bv = *(const bf16x8*)&Vts[nt * 16 + l16][ks * 32 + quad * 8];
                acc_o[nt] = __builtin_amdgcn_mfma_f32_16x16x32_bf16(ap, bv, acc_o[nt], 0, 0, 0);
            }
        }
        __syncthreads();   // Ks/Vts reads done before next stage
    }

#pragma unroll
    for (int nt = 0; nt < 4; ++nt)
#pragma unroll
        for (int i = 0; i < 4; ++i) {
            float o = acc_o[nt][i] / l_i[i];
            O[(qrow0 + w * 16 + quad * 4 + i) * 1024 + h * 64 + nt * 16 + l16] = f2bf(o);
        }
}

// ---------------- LayerNorm in place on [8192][1024] fp32 ----------------
__global__ __launch_bounds__(256) void ln_kernel(float* __restrict__ io,
    const float* __restrict__ gamma, const float* __restrict__ beta)
{
    int row = blockIdx.x;
    int tid = threadIdx.x;
    float* p = io + (size_t)row * 1024;
    float4 x = *reinterpret_cast<const float4*>(&p[tid << 2]);
    float s = x.x + x.y + x.z + x.w;
    float ss = fmaf(x.x, x.x, fmaf(x.y, x.y, fmaf(x.z, x.z, x.w * x.w)));
#pragma unroll
    for (int off = 32; off > 0; off >>= 1) {
        s  += __shfl_down(s, off);
        ss += __shfl_down(ss, off);
    }
    __shared__ float rs[4], rss[4];
    int lane = tid & 63, wid = tid >> 6;
    if (lane == 0) { rs[wid] = s; rss[wid] = ss; }
    __syncthreads();
    float S = rs[0] + rs[1] + rs[2] + rs[3];
    float SS = rss[0] + rss[1] + rss[2] + rss[3];
    float mu = S * (1.0f / 1024.0f);
    float var = SS * (1.0f / 1024.0f) - mu * mu;
    float rstd = rsqrtf(var + 1e-12f);
    float4 g = *reinterpret_cast<const float4*>(&gamma[tid << 2]);
    float4 be = *reinterpret_cast<const float4*>(&beta[tid << 2]);
    float4 o;
    o.x = (x.x - mu) * rstd * g.x + be.x;
    o.y = (x.y - mu) * rstd * g.y + be.y;
    o.z = (x.z - mu) * rstd * g.z + be.z;
    o.w = (x.w - mu) * rstd * g.w + be.w;
    *reinterpret_cast<float4*>(&p[tid << 2]) = o;
}

// ---------------- launch ----------------
extern "C" void kernel_launch(void* const* d_in, const int* in_sizes, int n_in,
                              void* d_out, int out_size, void* d_ws, size_t ws_size,
                              hipStream_t stream)
{
    (void)in_sizes; (void)n_in; (void)out_size; (void)ws_size;
    const float* hidden = (const float*)d_in[0];
    const float* Wq = (const float*)d_in[1];
    const float* bq = (const float*)d_in[2];
    const float* Wk = (const float*)d_in[3];
    const float* bk = (const float*)d_in[4];
    const float* Wv = (const float*)d_in[5];
    const float* bv = (const float*)d_in[6];
    const float* Wo = (const float*)d_in[7];
    const float* bo = (const float*)d_in[8];
    const float* g  = (const float*)d_in[9];
    const float* be = (const float*)d_in[10];
    float* out = (float*)d_out;

    u16* hb  = (u16*)d_ws;                       // [8192][1024] bf16 hidden
    u16* Wqt = hb  + (size_t)8192 * 1024;        // [1024][1024] Wq^T
    u16* Wkt = Wqt + (size_t)1024 * 1024;        // [512][1024]  Wk^T
    u16* Wvt = Wkt + (size_t)512 * 1024;         // [512][1024]  Wv^T (contiguous after Wkt)
    u16* Wot = Wvt + (size_t)512 * 1024;         // [1024][1024] Wo^T
    u16* Qb  = Wot + (size_t)1024 * 1024;        // [8192][1024] Q (then attn out)
    u16* KVb = Qb  + (size_t)8192 * 1024;        // [8192][1024] cols 0-511 K (512+ unused)
    u16* Vtb = KVb + (size_t)8192 * 1024;        // [4096][1024] V^T per (b,kvh)
    // total ~73 MB

    cvt_bf16_kernel<<<8192, 256, 0, stream>>>(hidden, hb, 8192 * 1024 / 4);
    cvt_t_kernel<<<dim3(16, 16), 256, 0, stream>>>(Wq, Wqt, 1024, 1024);
    cvt_t_kernel<<<dim3(8, 16),  256, 0, stream>>>(Wk, Wkt, 1024, 512);
    cvt_t_kernel<<<dim3(8, 16),  256, 0, stream>>>(Wv, Wvt, 1024, 512);
    cvt_t_kernel<<<dim3(16, 16), 256, 0, stream>>>(Wo, Wot, 1024, 1024);

    gemm_mfma<0><<<dim3(8, 64), 256, 0, stream>>>(hb, Wqt, bq, bq, nullptr, Qb, nullptr, 8192, 1024, 1024);
    gemm_mfma<2><<<dim3(8, 64), 256, 0, stream>>>(hb, Wkt, bk, bv, nullptr, KVb, Vtb, 8192, 1024, 1024);

    rope_bf16_kernel<<<16384, 256, 0, stream>>>(Qb, 4, 1024, 8192 * 16 * 32);
    rope_bf16_kernel<<<8192, 256, 0, stream>>>(KVb, 3, 1024, 8192 * 8 * 32);

    attn_mfma<<<dim3(16, 16, 8), 256, 0, stream>>>(Qb, KVb, Vtb, Qb);

    gemm_mfma<1><<<dim3(8, 64), 256, 0, stream>>>(Qb, Wot, bo, bo, hidden, out, nullptr, 8192, 1024, 1024);
    ln_kernel<<<8192, 256, 0, stream>>>(out, g, be);
}